// Round 17
// baseline (93.903 us; speedup 1.0000x reference)
//
#include <hip/hip_runtime.h>
#include <math.h>

#define B    64
#define DQ   512
#define DO   256
#define NH   8
#define DH   32
#define HW   1024
#define NCH  16     // s-chunks per image
#define CHS  64     // s per chunk

typedef float vf4 __attribute__((ext_vector_type(4)));

// async load + counted-wait primitives (compiler cannot reorder volatile asm)
#define VMWAIT(N)  do { asm volatile("s_waitcnt vmcnt(" #N ")" ::: "memory"); \
                        __builtin_amdgcn_sched_barrier(0); } while (0)

// ---------------------------------------------------------------- k1: qv = q @ w_q.T + b_q   (wave-per-output GEMV)
__global__ __launch_bounds__(256) void k1_qv(const float* __restrict__ q,
                                             const float* __restrict__ w_q,
                                             const float* __restrict__ b_q,
                                             float* __restrict__ qv) {
    int cg = blockIdx.x, b = blockIdx.y;
    int t = threadIdx.x;
    int wid = t >> 6, lane = t & 63;
    const float4* qrow = reinterpret_cast<const float4*>(q + (size_t)b*DQ);
    float4 q0 = qrow[lane*2], q1 = qrow[lane*2 + 1];
    #pragma unroll
    for (int r = 0; r < 4; ++r) {
        int c = cg*16 + wid*4 + r;
        const float4* wrow = reinterpret_cast<const float4*>(w_q + (size_t)c*DQ);
        float4 w0 = wrow[lane*2], w1 = wrow[lane*2 + 1];
        float acc = q0.x*w0.x + q0.y*w0.y + q0.z*w0.z + q0.w*w0.w
                  + q1.x*w1.x + q1.y*w1.y + q1.z*w1.z + q1.w*w1.w;
        #pragma unroll
        for (int k = 32; k > 0; k >>= 1) acc += __shfl_xor(acc, k);
        if (lane == 0) qv[b*DO + c] = acc + b_q[c];
    }
}

// ---------------------------------------------------------------- k2: fold qv into weights, INTERLEAVED transposed [b][c][16]
__global__ void k2_wqk(const float* __restrict__ qv,
                       const float* __restrict__ w_kc, const float* __restrict__ b_kc,
                       const float* __restrict__ w_kd, const float* __restrict__ b_kd,
                       const float* __restrict__ temp_c, const float* __restrict__ temp_d,
                       float* __restrict__ wqkT, float* __restrict__ qbc,
                       float* __restrict__ qbd) {
    int bn = blockIdx.x;              // b*8 + n
    int n  = bn & 7;
    int bb = bn >> 3;
    int t  = threadIdx.x;             // c
    __shared__ float qvs[DH];
    if (t < DH) qvs[t] = qv[bb*DO + n*DH + t];
    __syncthreads();
    float itc = 1.0f / temp_c[0];
    float itd = 1.0f / temp_d[0];
    float ac = 0.f, ad = 0.f;
    #pragma unroll
    for (int d = 0; d < DH; ++d) {
        float qd = qvs[d];
        ac += qd * w_kc[(n*DH + d)*DO + t];
        ad += qd * w_kd[(n*DH + d)*DO + t];
    }
    wqkT[((size_t)bb*DO + t)*16 + n]     = ac * itc;
    wqkT[((size_t)bb*DO + t)*16 + 8 + n] = ad * itd;
    if (t == 0) {
        float sc = 0.f;
        for (int d = 0; d < DH; ++d) sc += qvs[d]*b_kc[n*DH + d];
        qbc[bn] = sc * itc;
    }
    if (t == 1) {
        float sd = 0.f;
        for (int d = 0; d < DH; ++d) sd += qvs[d]*b_kd[n*DH + d];
        qbd[bn] = sd * itd;
    }
}

// ---------------------------------------------------------------- k3q: k3n + inline-asm async loads, counted vmcnt pipeline
// grid (NCH=16, B) = 1024 blocks, block 512 (8 waves), 34 KB LDS.
__global__ __launch_bounds__(512, 4)
void k3q(const float* __restrict__ v,
         const float* __restrict__ wqkT,
         const float* __restrict__ qbc,  const float* __restrict__ qbd,
         float* __restrict__ gate, float* __restrict__ pvp, float* __restrict__ mz) {
    __shared__ float pc[8*NH*CHS];       // 16 KB collect partials [csub][n][s]
    __shared__ float pd[8*NH*CHS];       // 16 KB diffuse partials
    __shared__ float e_lds[NH][CHS];     // 2 KB
    int ch = blockIdx.x, b = blockIdx.y;
    int t  = threadIdx.x;
    int s0 = ch*CHS;
    int bn0 = b*NH;
    int lane = t & 63;
    int csub = __builtin_amdgcn_readfirstlane(t >> 6);

    // ---- phase 1: 4 groups of 8 async loads, 2-deep pipeline with vmcnt(8)
    {
        const float* vb = v + (size_t)b*DO*HW + s0 + lane;
        const float* wt = wqkT + (size_t)b*DO*16;      // wave-uniform base
        int cbase = csub*32;
        float vv[32];
        float acc_c[NH] = {0,0,0,0,0,0,0,0};
        float acc_d[NH] = {0,0,0,0,0,0,0,0};

#define ISSUE8(g)                                                              \
        {                                                                      \
            _Pragma("unroll")                                                  \
            for (int j = 0; j < 8; ++j)                                        \
                asm volatile("global_load_dword %0, %1, off"                   \
                             : "=v"(vv[(g)*8 + j])                             \
                             : "v"(vb + (size_t)(cbase + (g)*8 + j)*HW));      \
        }
#define CONSUME8(g)                                                            \
        {                                                                      \
            _Pragma("unroll")                                                  \
            for (int cc = (g)*8; cc < (g)*8 + 8; ++cc) {                       \
                float x = vv[cc];                                              \
                const float* wrow = wt + (size_t)(cbase + cc)*16;              \
                _Pragma("unroll")                                              \
                for (int n = 0; n < NH; ++n) {                                 \
                    acc_c[n] = fmaf(wrow[n],   x, acc_c[n]);                   \
                    acc_d[n] = fmaf(wrow[8+n], x, acc_d[n]);                   \
                }                                                              \
            }                                                                  \
        }

        ISSUE8(0); ISSUE8(1);
        VMWAIT(8);  CONSUME8(0); ISSUE8(2);
        VMWAIT(8);  CONSUME8(1); ISSUE8(3);
        VMWAIT(8);  CONSUME8(2);
        VMWAIT(0);  CONSUME8(3);
#undef ISSUE8
#undef CONSUME8

        #pragma unroll
        for (int n = 0; n < NH; ++n) {
            pc[(csub*NH + n)*CHS + lane] = acc_c[n];
            pd[(csub*NH + n)*CHS + lane] = acc_d[n];
        }
    }
    __syncthreads();

    // ---- phase 2: wave n combines csub partials for head n; softmax + gate, wave-local
    {
        int n = csub;
        float lc = qbc[bn0+n];
        float ld = qbd[bn0+n];
        #pragma unroll
        for (int k = 0; k < 8; ++k) {
            lc += pc[(k*NH + n)*CHS + lane];
            ld += pd[(k*NH + n)*CHS + lane];
        }
        gate[(size_t)(bn0+n)*HW + s0 + lane] = 1.0f/(1.0f + __expf(-ld));
        float m = lc;
        #pragma unroll
        for (int k = 32; k > 0; k >>= 1) m = fmaxf(m, __shfl_xor(m, k));
        float e = __expf(lc - m);
        e_lds[n][lane] = e;
        float z = e;
        #pragma unroll
        for (int k = 32; k > 0; k >>= 1) z += __shfl_xor(z, k);
        if (lane == 0) {
            float* mzp = mz + ((size_t)(b*NCH + ch)*NH + n)*2;
            mzp[0] = m; mzp[1] = z;
        }
    }
    __syncthreads();

    // ---- phase 3: pool; ALL 16 float4 loads async in flight, single drain
    {
        int ng = t >> 8;                 // 0 or 1
        int c  = t & 255;
        const float* vrow = v + ((size_t)(b*DO + c))*HW + s0;
        vf4 vr[16];
        #pragma unroll
        for (int j = 0; j < 16; ++j)
            asm volatile("global_load_dwordx4 %0, %1, off"
                         : "=v"(vr[j]) : "v"(vrow + j*4));
        VMWAIT(0);

        float a0 = 0.f, a1 = 0.f, a2 = 0.f, a3 = 0.f;
        #pragma unroll
        for (int j = 0; j < 16; ++j) {
            vf4 v4 = vr[j];
            float4 e0 = *reinterpret_cast<const float4*>(&e_lds[ng*4+0][j*4]);
            float4 e1 = *reinterpret_cast<const float4*>(&e_lds[ng*4+1][j*4]);
            float4 e2 = *reinterpret_cast<const float4*>(&e_lds[ng*4+2][j*4]);
            float4 e3 = *reinterpret_cast<const float4*>(&e_lds[ng*4+3][j*4]);
            a0 += v4.x*e0.x + v4.y*e0.y + v4.z*e0.z + v4.w*e0.w;
            a1 += v4.x*e1.x + v4.y*e1.y + v4.z*e1.z + v4.w*e1.w;
            a2 += v4.x*e2.x + v4.y*e2.y + v4.z*e2.z + v4.w*e2.w;
            a3 += v4.x*e3.x + v4.y*e3.y + v4.z*e3.z + v4.w*e3.w;
        }
        size_t pb = ((size_t)(b*NCH + ch)*NH + ng*4)*DO + c;
        pvp[pb]        = a0;
        pvp[pb + DO]   = a1;
        pvp[pb + 2*DO] = a2;
        pvp[pb + 3*DO] = a3;
    }
}

// ---------------------------------------------------------------- k4c: softmax-scale combine of 16 chunks + GEMV
__global__ void k4c(const float* __restrict__ pvp, const float* __restrict__ mz,
                    const float* __restrict__ w_v, const float* __restrict__ b_v,
                    float* __restrict__ attn) {
    __shared__ float scale[NCH][NH];
    __shared__ float pv_lds[NH*DO];
    int b = blockIdx.x, t = threadIdx.x;
    if (t < NH) {
        int n = t;
        float M = -1e30f;
        for (int ch = 0; ch < NCH; ++ch)
            M = fmaxf(M, mz[((size_t)(b*NCH+ch)*NH+n)*2]);
        float Z = 0.f;
        for (int ch = 0; ch < NCH; ++ch) {
            float sc = __expf(mz[((size_t)(b*NCH+ch)*NH+n)*2] - M);
            Z += sc * mz[((size_t)(b*NCH+ch)*NH+n)*2 + 1];
            scale[ch][n] = sc;
        }
        float inv = 1.0f/Z;
        for (int ch = 0; ch < NCH; ++ch) scale[ch][n] *= inv;
    }
    __syncthreads();
    #pragma unroll
    for (int r = 0; r < 2; ++r) {
        int i4 = t + r*256;              // float4 index, head = i4/64
        int n  = i4 >> 6;
        float4 s = make_float4(0.f, 0.f, 0.f, 0.f);
        #pragma unroll 4
        for (int ch = 0; ch < NCH; ++ch) {
            float sc = scale[ch][n];
            float4 p = reinterpret_cast<const float4*>(pvp + (size_t)(b*NCH + ch)*NH*DO)[i4];
            s.x = fmaf(sc, p.x, s.x); s.y = fmaf(sc, p.y, s.y);
            s.z = fmaf(sc, p.z, s.z); s.w = fmaf(sc, p.w, s.w);
        }
        *reinterpret_cast<float4*>(&pv_lds[i4*4]) = s;
    }
    __syncthreads();
    int n = t >> 5;
    float acc = b_v[t];
    const float4* w4 = reinterpret_cast<const float4*>(w_v + t*DO);
    #pragma unroll 4
    for (int c4 = 0; c4 < DO/4; ++c4) {
        float4 wv = w4[c4];
        int c = c4*4;
        acc += pv_lds[n*DO+c]*wv.x + pv_lds[n*DO+c+1]*wv.y + pv_lds[n*DO+c+2]*wv.z + pv_lds[n*DO+c+3]*wv.w;
    }
    attn[b*DO + t] = acc;
}

// ---------------------------------------------------------------- k5: out = leaky(bn(gate[s^T]*attn + v))
__global__ void k5_out(const float* __restrict__ v, const float* __restrict__ gate,
                       const float* __restrict__ attn,
                       const float* __restrict__ bn_g, const float* __restrict__ bn_b,
                       const float* __restrict__ bn_m, const float* __restrict__ bn_v,
                       float* __restrict__ out) {
    int c = blockIdx.x, b = blockIdx.y;
    int n = c >> 5, d = c & 31;
    int t = threadIdx.x;
    __shared__ float g[32*33];             // stride 33 kills transpose bank conflicts
    float4 gv = reinterpret_cast<const float4*>(gate + (b*NH + n)*HW)[t];
    int s0 = t*4;
    int ga = s0 >> 5, gb = s0 & 31;
    g[ga*33 + gb + 0] = gv.x;
    g[ga*33 + gb + 1] = gv.y;
    g[ga*33 + gb + 2] = gv.z;
    g[ga*33 + gb + 3] = gv.w;
    __syncthreads();
    float av   = attn[(b*NH + n)*DH + d];
    float inv  = bn_g[c] / sqrtf(bn_v[c] + 1e-5f);
    float mean = bn_m[c], beta = bn_b[c];
    size_t base = ((size_t)(b*DO + c))*HW;
    float4 r4 = reinterpret_cast<const float4*>(v + base)[t];
    int l = 4*t;
    int i_ = l >> 5, j_ = l & 31;          // gate index s = j*32 + i
    float x0 = g[(j_+0)*33 + i_]*av + r4.x;
    float x1 = g[(j_+1)*33 + i_]*av + r4.y;
    float x2 = g[(j_+2)*33 + i_]*av + r4.z;
    float x3 = g[(j_+3)*33 + i_]*av + r4.w;
    float y0 = (x0 - mean)*inv + beta; y0 = y0 >= 0.f ? y0 : 0.1f*y0;
    float y1 = (x1 - mean)*inv + beta; y1 = y1 >= 0.f ? y1 : 0.1f*y1;
    float y2 = (x2 - mean)*inv + beta; y2 = y2 >= 0.f ? y2 : 0.1f*y2;
    float y3 = (x3 - mean)*inv + beta; y3 = y3 >= 0.f ? y3 : 0.1f*y3;
    reinterpret_cast<float4*>(out + base)[t] = make_float4(y0, y1, y2, y3);
}

// ----------------------------------------------------------------
extern "C" void kernel_launch(void* const* d_in, const int* in_sizes, int n_in,
                              void* d_out, int out_size, void* d_ws, size_t ws_size,
                              hipStream_t stream) {
    const float* q      = (const float*)d_in[0];
    const float* v      = (const float*)d_in[1];
    const float* w_q    = (const float*)d_in[2];
    const float* b_q    = (const float*)d_in[3];
    const float* w_kc   = (const float*)d_in[4];
    const float* b_kc   = (const float*)d_in[5];
    const float* w_kd   = (const float*)d_in[6];
    const float* b_kd   = (const float*)d_in[7];
    const float* w_v    = (const float*)d_in[8];
    const float* b_v    = (const float*)d_in[9];
    const float* temp_c = (const float*)d_in[10];
    const float* temp_d = (const float*)d_in[11];
    const float* bn_g   = (const float*)d_in[12];
    const float* bn_b   = (const float*)d_in[13];
    const float* bn_m   = (const float*)d_in[14];
    const float* bn_v   = (const float*)d_in[15];
    float* out = (float*)d_out;

    float* ws   = (float*)d_ws;
    float* qv   = ws;                     // B*DO         = 16384
    float* wqkT = qv   + B*DO;            // B*DO*16      = 262144
    float* qbc  = wqkT + (size_t)B*DO*16; // 512
    float* qbd  = qbc  + B*NH;            // 512
    float* gate = qbd  + B*NH;            // B*NH*HW      = 524288
    float* mz   = gate + B*NH*HW;         // B*NCH*NH*2   = 16384
    float* pvp  = mz   + B*NCH*NH*2;      // B*NCH*NH*DO  = 2097152
    float* attn = pvp  + (size_t)B*NCH*NH*DO; // B*DO     = 16384

    k1_qv <<<dim3(16, B),    256, 0, stream>>>(q, w_q, b_q, qv);
    k2_wqk<<<B*NH,           256, 0, stream>>>(qv, w_kc, b_kc, w_kd, b_kd, temp_c, temp_d,
                                               wqkT, qbc, qbd);
    k3q   <<<dim3(NCH, B),   512, 0, stream>>>(v, wqkT, qbc, qbd, gate, pvp, mz);
    k4c   <<<B,              256, 0, stream>>>(pvp, mz, w_v, b_v, attn);
    k5_out<<<dim3(DO, B),    256, 0, stream>>>(v, gate, attn, bn_g, bn_b, bn_m, bn_v, out);
}

// Round 18
// 78.526 us; speedup vs baseline: 1.1958x; 1.1958x over previous
//
#include <hip/hip_runtime.h>
#include <math.h>

#define B    64
#define DQ   512
#define DO   256
#define NH   8
#define DH   32
#define HW   1024
#define NCH  16     // s-chunks per image
#define CHS  64     // s per chunk

// ---------------------------------------------------------------- k1: qv = q @ w_q.T + b_q   (wave-per-output GEMV)
__global__ __launch_bounds__(256) void k1_qv(const float* __restrict__ q,
                                             const float* __restrict__ w_q,
                                             const float* __restrict__ b_q,
                                             float* __restrict__ qv) {
    int cg = blockIdx.x, b = blockIdx.y;
    int t = threadIdx.x;
    int wid = t >> 6, lane = t & 63;
    const float4* qrow = reinterpret_cast<const float4*>(q + (size_t)b*DQ);
    float4 q0 = qrow[lane*2], q1 = qrow[lane*2 + 1];
    #pragma unroll
    for (int r = 0; r < 4; ++r) {
        int c = cg*16 + wid*4 + r;
        const float4* wrow = reinterpret_cast<const float4*>(w_q + (size_t)c*DQ);
        float4 w0 = wrow[lane*2], w1 = wrow[lane*2 + 1];
        float acc = q0.x*w0.x + q0.y*w0.y + q0.z*w0.z + q0.w*w0.w
                  + q1.x*w1.x + q1.y*w1.y + q1.z*w1.z + q1.w*w1.w;
        #pragma unroll
        for (int k = 32; k > 0; k >>= 1) acc += __shfl_xor(acc, k);
        if (lane == 0) qv[b*DO + c] = acc + b_q[c];
    }
}

// ---------------------------------------------------------------- k2: fold qv into weights, PACKED [bn][c][2] = {wc, wd}
__global__ void k2_wqk(const float* __restrict__ qv,
                       const float* __restrict__ w_kc, const float* __restrict__ b_kc,
                       const float* __restrict__ w_kd, const float* __restrict__ b_kd,
                       const float* __restrict__ temp_c, const float* __restrict__ temp_d,
                       float* __restrict__ wpack, float* __restrict__ qbc,
                       float* __restrict__ qbd) {
    int bn = blockIdx.x;              // b*8 + n
    int n  = bn & 7;
    int bb = bn >> 3;
    int t  = threadIdx.x;             // c
    __shared__ float qvs[DH];
    if (t < DH) qvs[t] = qv[bb*DO + n*DH + t];
    __syncthreads();
    float itc = 1.0f / temp_c[0];
    float itd = 1.0f / temp_d[0];
    float ac = 0.f, ad = 0.f;
    #pragma unroll
    for (int d = 0; d < DH; ++d) {
        float qd = qvs[d];
        ac += qd * w_kc[(n*DH + d)*DO + t];
        ad += qd * w_kd[(n*DH + d)*DO + t];
    }
    wpack[((size_t)bn*DO + t)*2 + 0] = ac * itc;
    wpack[((size_t)bn*DO + t)*2 + 1] = ad * itd;
    if (t == 0) {
        float sc = 0.f;
        for (int d = 0; d < DH; ++d) sc += qvs[d]*b_kc[n*DH + d];
        qbc[bn] = sc * itc;
    }
    if (t == 1) {
        float sd = 0.f;
        for (int d = 0; d < DH; ++d) sd += qvs[d]*b_kd[n*DH + d];
        qbd[bn] = sd * itd;
    }
}

// ---------------------------------------------------------------- k3r: swizzled-LDS v slice; b128-only consumption
// grid (NCH=16, B) = 1024 blocks, block 512 (8 waves), 66 KB LDS -> 2 blocks/CU.
// Stage: 1 coalesced v pass (proven k3j pattern). Phase 1: wave w = head w,
// lane = (c_off = lane>>4, s4 = lane&15); ds_read_b128 + packed-w float2;
// c-reduce via 2 shuffles. Phase 3: pool from LDS (proven k3j pattern).
__global__ __launch_bounds__(512, 2)
void k3r(const float* __restrict__ v,
         const float* __restrict__ wpack,
         const float* __restrict__ qbc,  const float* __restrict__ qbd,
         float* __restrict__ gate, float* __restrict__ pvp, float* __restrict__ mz) {
    __shared__ float vbuf[DO][CHS];      // 64 KB swizzled v slice
    __shared__ float e_lds[NH][CHS];     // 2 KB
    int ch = blockIdx.x, b = blockIdx.y;
    int t  = threadIdx.x;
    int s0 = ch*CHS;
    int bn0 = b*NH;
    int lane = t & 63;
    int w = __builtin_amdgcn_readfirstlane(t >> 6);   // wave id = head

    // ---- stage: 8 coalesced float4 loads per thread, swizzled store
    {
        int s4 = t & 15, srow = t >> 4;               // srow in [0,32)
        const float* vb = v + (size_t)b*DO*HW + s0;
        int idx4 = (s4 ^ (srow & 15)) * 4;            // c&15 == srow&15 for all tiles
        #pragma unroll
        for (int k = 0; k < 8; ++k) {
            float4 r = *reinterpret_cast<const float4*>(vb + (size_t)(k*32+srow)*HW + s4*4);
            *reinterpret_cast<float4*>(&vbuf[k*32+srow][idx4]) = r;
        }
    }
    __syncthreads();

    // ---- phase 1: head-w logits, 4 s per lane via b128, c split over lane>>4
    float ac0=0.f, ac1=0.f, ac2=0.f, ac3=0.f;
    float ad0=0.f, ad1=0.f, ad2=0.f, ad3=0.f;
    {
        int c_off = lane >> 4, s4 = lane & 15;
        const float2* wp = reinterpret_cast<const float2*>(wpack) + (size_t)(bn0 + w)*DO;
        #pragma unroll 8
        for (int cc = 0; cc < 64; ++cc) {
            int c = cc*4 + c_off;
            float4 v4 = *reinterpret_cast<const float4*>(&vbuf[c][(s4 ^ (c & 15))*4]);
            float2 wv = wp[c];                         // 4 distinct addrs, L1-hot
            ac0 = fmaf(wv.x, v4.x, ac0); ac1 = fmaf(wv.x, v4.y, ac1);
            ac2 = fmaf(wv.x, v4.z, ac2); ac3 = fmaf(wv.x, v4.w, ac3);
            ad0 = fmaf(wv.y, v4.x, ad0); ad1 = fmaf(wv.y, v4.y, ad1);
            ad2 = fmaf(wv.y, v4.z, ad2); ad3 = fmaf(wv.y, v4.w, ad3);
        }
        // reduce over the 4 c_off groups (lane bits 4,5)
        ac0 += __shfl_xor(ac0, 16); ac0 += __shfl_xor(ac0, 32);
        ac1 += __shfl_xor(ac1, 16); ac1 += __shfl_xor(ac1, 32);
        ac2 += __shfl_xor(ac2, 16); ac2 += __shfl_xor(ac2, 32);
        ac3 += __shfl_xor(ac3, 16); ac3 += __shfl_xor(ac3, 32);
        ad0 += __shfl_xor(ad0, 16); ad0 += __shfl_xor(ad0, 32);
        ad1 += __shfl_xor(ad1, 16); ad1 += __shfl_xor(ad1, 32);
        ad2 += __shfl_xor(ad2, 16); ad2 += __shfl_xor(ad2, 32);
        ad3 += __shfl_xor(ad3, 16); ad3 += __shfl_xor(ad3, 32);
    }

    // ---- phase 2: wave-local gate + softmax stats over 64 s (4/lane x 16 s4)
    {
        int s4 = lane & 15;
        float qc = qbc[bn0 + w], qd = qbd[bn0 + w];
        float l0 = ac0 + qc, l1 = ac1 + qc, l2 = ac2 + qc, l3 = ac3 + qc;
        float g0 = 1.0f/(1.0f + __expf(-(ad0 + qd)));
        float g1 = 1.0f/(1.0f + __expf(-(ad1 + qd)));
        float g2 = 1.0f/(1.0f + __expf(-(ad2 + qd)));
        float g3 = 1.0f/(1.0f + __expf(-(ad3 + qd)));
        if (lane < 16)
            *reinterpret_cast<float4*>(gate + (size_t)(bn0 + w)*HW + s0 + s4*4)
                = make_float4(g0, g1, g2, g3);

        float m = fmaxf(fmaxf(l0, l1), fmaxf(l2, l3));
        #pragma unroll
        for (int k = 1; k <= 8; k <<= 1) m = fmaxf(m, __shfl_xor(m, k));
        float e0 = __expf(l0 - m), e1 = __expf(l1 - m);
        float e2 = __expf(l2 - m), e3 = __expf(l3 - m);
        float z = e0 + e1 + e2 + e3;
        #pragma unroll
        for (int k = 1; k <= 8; k <<= 1) z += __shfl_xor(z, k);
        if (lane < 16)
            *reinterpret_cast<float4*>(&e_lds[w][s4*4]) = make_float4(e0, e1, e2, e3);
        if (lane == 0) {
            float* mzp = mz + ((size_t)(b*NCH + ch)*NH + w)*2;
            mzp[0] = m; mzp[1] = z;
        }
    }
    __syncthreads();

    // ---- phase 3: pool from LDS; thread -> (c, 4 heads); zero global v reads
    {
        int c = t & 255, nh = t >> 8;
        int cx = c & 15;
        float a0 = 0.f, a1 = 0.f, a2 = 0.f, a3 = 0.f;
        #pragma unroll
        for (int j = 0; j < 16; ++j) {
            float4 v4 = *reinterpret_cast<const float4*>(&vbuf[c][(j ^ cx)*4]);
            float4 e0 = *reinterpret_cast<const float4*>(&e_lds[nh*4+0][j*4]);
            float4 e1 = *reinterpret_cast<const float4*>(&e_lds[nh*4+1][j*4]);
            float4 e2 = *reinterpret_cast<const float4*>(&e_lds[nh*4+2][j*4]);
            float4 e3 = *reinterpret_cast<const float4*>(&e_lds[nh*4+3][j*4]);
            a0 += v4.x*e0.x + v4.y*e0.y + v4.z*e0.z + v4.w*e0.w;
            a1 += v4.x*e1.x + v4.y*e1.y + v4.z*e1.z + v4.w*e1.w;
            a2 += v4.x*e2.x + v4.y*e2.y + v4.z*e2.z + v4.w*e2.w;
            a3 += v4.x*e3.x + v4.y*e3.y + v4.z*e3.z + v4.w*e3.w;
        }
        size_t pb = ((size_t)(b*NCH + ch)*NH + nh*4)*DO + c;
        pvp[pb]        = a0;
        pvp[pb + DO]   = a1;
        pvp[pb + 2*DO] = a2;
        pvp[pb + 3*DO] = a3;
    }
}

// ---------------------------------------------------------------- k4c: softmax-scale combine of 16 chunks + GEMV
__global__ void k4c(const float* __restrict__ pvp, const float* __restrict__ mz,
                    const float* __restrict__ w_v, const float* __restrict__ b_v,
                    float* __restrict__ attn) {
    __shared__ float scale[NCH][NH];
    __shared__ float pv_lds[NH*DO];
    int b = blockIdx.x, t = threadIdx.x;
    if (t < NH) {
        int n = t;
        float M = -1e30f;
        for (int ch = 0; ch < NCH; ++ch)
            M = fmaxf(M, mz[((size_t)(b*NCH+ch)*NH+n)*2]);
        float Z = 0.f;
        for (int ch = 0; ch < NCH; ++ch) {
            float sc = __expf(mz[((size_t)(b*NCH+ch)*NH+n)*2] - M);
            Z += sc * mz[((size_t)(b*NCH+ch)*NH+n)*2 + 1];
            scale[ch][n] = sc;
        }
        float inv = 1.0f/Z;
        for (int ch = 0; ch < NCH; ++ch) scale[ch][n] *= inv;
    }
    __syncthreads();
    #pragma unroll
    for (int r = 0; r < 2; ++r) {
        int i4 = t + r*256;              // float4 index, head = i4/64
        int n  = i4 >> 6;
        float4 s = make_float4(0.f, 0.f, 0.f, 0.f);
        #pragma unroll 4
        for (int ch = 0; ch < NCH; ++ch) {
            float sc = scale[ch][n];
            float4 p = reinterpret_cast<const float4*>(pvp + (size_t)(b*NCH + ch)*NH*DO)[i4];
            s.x = fmaf(sc, p.x, s.x); s.y = fmaf(sc, p.y, s.y);
            s.z = fmaf(sc, p.z, s.z); s.w = fmaf(sc, p.w, s.w);
        }
        *reinterpret_cast<float4*>(&pv_lds[i4*4]) = s;
    }
    __syncthreads();
    int n = t >> 5;
    float acc = b_v[t];
    const float4* w4 = reinterpret_cast<const float4*>(w_v + t*DO);
    #pragma unroll 4
    for (int c4 = 0; c4 < DO/4; ++c4) {
        float4 wv = w4[c4];
        int c = c4*4;
        acc += pv_lds[n*DO+c]*wv.x + pv_lds[n*DO+c+1]*wv.y + pv_lds[n*DO+c+2]*wv.z + pv_lds[n*DO+c+3]*wv.w;
    }
    attn[b*DO + t] = acc;
}

// ---------------------------------------------------------------- k5: out = leaky(bn(gate[s^T]*attn + v))
__global__ void k5_out(const float* __restrict__ v, const float* __restrict__ gate,
                       const float* __restrict__ attn,
                       const float* __restrict__ bn_g, const float* __restrict__ bn_b,
                       const float* __restrict__ bn_m, const float* __restrict__ bn_v,
                       float* __restrict__ out) {
    int c = blockIdx.x, b = blockIdx.y;
    int n = c >> 5, d = c & 31;
    int t = threadIdx.x;
    __shared__ float g[32*33];             // stride 33 kills transpose bank conflicts
    float4 gv = reinterpret_cast<const float4*>(gate + (b*NH + n)*HW)[t];
    int s0 = t*4;
    int ga = s0 >> 5, gb = s0 & 31;
    g[ga*33 + gb + 0] = gv.x;
    g[ga*33 + gb + 1] = gv.y;
    g[ga*33 + gb + 2] = gv.z;
    g[ga*33 + gb + 3] = gv.w;
    __syncthreads();
    float av   = attn[(b*NH + n)*DH + d];
    float inv  = bn_g[c] / sqrtf(bn_v[c] + 1e-5f);
    float mean = bn_m[c], beta = bn_b[c];
    size_t base = ((size_t)(b*DO + c))*HW;
    float4 r4 = reinterpret_cast<const float4*>(v + base)[t];
    int l = 4*t;
    int i_ = l >> 5, j_ = l & 31;          // gate index s = j*32 + i
    float x0 = g[(j_+0)*33 + i_]*av + r4.x;
    float x1 = g[(j_+1)*33 + i_]*av + r4.y;
    float x2 = g[(j_+2)*33 + i_]*av + r4.z;
    float x3 = g[(j_+3)*33 + i_]*av + r4.w;
    float y0 = (x0 - mean)*inv + beta; y0 = y0 >= 0.f ? y0 : 0.1f*y0;
    float y1 = (x1 - mean)*inv + beta; y1 = y1 >= 0.f ? y1 : 0.1f*y1;
    float y2 = (x2 - mean)*inv + beta; y2 = y2 >= 0.f ? y2 : 0.1f*y2;
    float y3 = (x3 - mean)*inv + beta; y3 = y3 >= 0.f ? y3 : 0.1f*y3;
    reinterpret_cast<float4*>(out + base)[t] = make_float4(y0, y1, y2, y3);
}

// ----------------------------------------------------------------
extern "C" void kernel_launch(void* const* d_in, const int* in_sizes, int n_in,
                              void* d_out, int out_size, void* d_ws, size_t ws_size,
                              hipStream_t stream) {
    const float* q      = (const float*)d_in[0];
    const float* v      = (const float*)d_in[1];
    const float* w_q    = (const float*)d_in[2];
    const float* b_q    = (const float*)d_in[3];
    const float* w_kc   = (const float*)d_in[4];
    const float* b_kc   = (const float*)d_in[5];
    const float* w_kd   = (const float*)d_in[6];
    const float* b_kd   = (const float*)d_in[7];
    const float* w_v    = (const float*)d_in[8];
    const float* b_v    = (const float*)d_in[9];
    const float* temp_c = (const float*)d_in[10];
    const float* temp_d = (const float*)d_in[11];
    const float* bn_g   = (const float*)d_in[12];
    const float* bn_b   = (const float*)d_in[13];
    const float* bn_m   = (const float*)d_in[14];
    const float* bn_v   = (const float*)d_in[15];
    float* out = (float*)d_out;

    float* ws    = (float*)d_ws;
    float* qv    = ws;                       // B*DO          = 16384
    float* wpack = qv    + B*DO;             // B*NH*DO*2     = 262144
    float* qbc   = wpack + (size_t)B*NH*DO*2; // 512
    float* qbd   = qbc   + B*NH;             // 512
    float* gate  = qbd   + B*NH;             // B*NH*HW       = 524288
    float* mz    = gate  + B*NH*HW;          // B*NCH*NH*2    = 16384
    float* pvp   = mz    + B*NCH*NH*2;       // B*NCH*NH*DO   = 2097152
    float* attn  = pvp   + (size_t)B*NCH*NH*DO; // B*DO       = 16384

    k1_qv <<<dim3(16, B),    256, 0, stream>>>(q, w_q, b_q, qv);
    k2_wqk<<<B*NH,           256, 0, stream>>>(qv, w_kc, b_kc, w_kd, b_kd, temp_c, temp_d,
                                               wpack, qbc, qbd);
    k3r   <<<dim3(NCH, B),   512, 0, stream>>>(v, wpack, qbc, qbd, gate, pvp, mz);
    k4c   <<<B,              256, 0, stream>>>(pvp, mz, w_v, b_v, attn);
    k5_out<<<dim3(DO, B),    256, 0, stream>>>(v, gate, attn, bn_g, bn_b, bn_m, bn_v, out);
}